// Round 1
// baseline (698.115 us; speedup 1.0000x reference)
//
#include <hip/hip_runtime.h>

// BatchAdaptiveConv2d: out[b,o,y,x] = sum_{i,dy,dx} x[b,i,y+dy-1,x+dx-1] *
//                      weights[i,o,dy,dx] * wadapt[b,i]  + bias[o]*badapt[b,o]
// wadapt = [cond|lpe] @ wa_w.T + wa_b   (B x Cin)
// badapt = [cond|lpe] @ ba_w.T + ba_b   (B x Cout)
//
// Strategy R0: fp32 direct conv, block-tiled. Compute-bound on fp32 VALU
// (floor 123 us). Weights scaled per-(b,i) and staged in LDS o-contiguous
// (broadcast float4 reads); x staged per-4-channel chunk with halo.

#define B_    16
#define CIN   32
#define COUT  32
#define H_    256
#define W_    256
#define EMB2  512

#define TILE_H 32
#define TILE_W 64
#define XROWS  34          // TILE_H + 2 halo
#define XCOLS  66          // TILE_W + 2 halo
#define XPITCH 68          // pad to 68 floats = 272 B (16B-aligned rows)
#define CHUNK  4

// ---------------- kernel 1: adapt coefficients ----------------
// ws layout: ws[0..511] = wadapt[b][i], ws[512..1023] = biasmod[b][o]
__global__ __launch_bounds__(256) void adapt_kernel(
    const float* __restrict__ cond, const float* __restrict__ lpe,
    const float* __restrict__ wa_w, const float* __restrict__ wa_b,
    const float* __restrict__ ba_w, const float* __restrict__ ba_b,
    const float* __restrict__ bias, float* __restrict__ ws)
{
    __shared__ float iv[EMB2];
    __shared__ float partial[64][4];
    const int b = blockIdx.x;
    const int t = threadIdx.x;

    iv[t]       = cond[b*256 + t];
    iv[t + 256] = lpe[b*256 + t];
    __syncthreads();

    const int out  = t & 63;   // 0..31 -> wadapt, 32..63 -> badapt
    const int part = t >> 6;   // 4-way split of the 512-dot
    const float* row = (out < 32) ? (wa_w + out*EMB2) : (ba_w + (out-32)*EMB2);
    float s = 0.f;
    #pragma unroll 8
    for (int j = part*128; j < part*128 + 128; ++j) s += iv[j] * row[j];
    partial[out][part] = s;
    __syncthreads();

    if (t < 64) {
        float v = partial[t][0] + partial[t][1] + partial[t][2] + partial[t][3];
        if (t < 32) {
            ws[b*32 + t] = v + wa_b[t];
        } else {
            int o = t - 32;
            ws[512 + b*32 + o] = bias[o] * (v + ba_b[o]);
        }
    }
}

// ---------------- kernel 2: modulated conv ----------------
// grid (W/64, H/32, B*2); block 256. Each block: 32x64 pixels, 16 out-chans.
// Per thread: 2 rows x 4 cols pixels, 16 out-chans -> acc[16][2][4] = 128 VGPR.
__global__ __launch_bounds__(256, 2) void conv_kernel(
    const float* __restrict__ x, const float* __restrict__ weights,
    const float* __restrict__ ws, float* __restrict__ out)
{
    __shared__ float w_lds[CIN*9*16];               // [i][tap][ol], ol contiguous
    __shared__ float x_tile[CHUNK][XROWS][XPITCH];  // halo'd chunk of 4 in-chans

    const int tid = threadIdx.x;
    const int tx4 = tid & 15;       // 16 col-groups of 4
    const int ty  = tid >> 4;       // 16 row-groups of 2
    const int bx  = blockIdx.x;
    const int by  = blockIdx.y;
    const int b   = blockIdx.z >> 1;
    const int oh  = blockIdx.z & 1; // which half of the 32 out-chans

    const float* wadapt  = ws + b*32;
    const float* biasmod = ws + 512 + b*32;

    // stage scaled weights: w_lds[i*144 + tap*16 + ol] = W[i][oh*16+ol][tap] * wadapt[i]
    for (int idx = tid; idx < CIN*9*16; idx += 256) {
        int i   = idx / 144;
        int r   = idx - i*144;
        int tap = r >> 4;
        int ol  = r & 15;
        int o   = oh*16 + ol;
        w_lds[idx] = weights[(i*COUT + o)*9 + tap] * wadapt[i];
    }

    float acc[16][2][4];
    #pragma unroll
    for (int o = 0; o < 16; ++o)
        #pragma unroll
        for (int u = 0; u < 2; ++u)
            #pragma unroll
            for (int v = 0; v < 4; ++v) acc[o][u][v] = 0.f;

    const int y0 = by * TILE_H;
    const int x0 = bx * TILE_W;

    for (int c = 0; c < CIN/CHUNK; ++c) {
        __syncthreads();
        // stage x chunk with halo (zero-pad at image borders)
        for (int e = tid; e < CHUNK*XROWS*XCOLS; e += 256) {
            int ic = e / (XROWS*XCOLS);
            int r2 = e - ic*(XROWS*XCOLS);
            int rr = r2 / XCOLS;
            int cc = r2 - rr*XCOLS;
            int gy = y0 + rr - 1;
            int gx = x0 + cc - 1;
            float v = 0.f;
            if (gy >= 0 && gy < H_ && gx >= 0 && gx < W_)
                v = x[((size_t)(b*CIN + c*CHUNK + ic)*H_ + gy)*W_ + gx];
            x_tile[ic][rr][cc] = v;
        }
        __syncthreads();

        for (int ic = 0; ic < CHUNK; ++ic) {
            const int i = c*CHUNK + ic;
            // 4x6 input window covering 2x4 output pixels, 3x3 taps
            float xr[4][6];
            #pragma unroll
            for (int j = 0; j < 4; ++j)
                #pragma unroll
                for (int m = 0; m < 6; ++m)
                    xr[j][m] = x_tile[ic][2*ty + j][tx4*4 + m];

            #pragma unroll
            for (int og = 0; og < 4; ++og) {
                float4 w4[9];
                #pragma unroll
                for (int tap = 0; tap < 9; ++tap)
                    w4[tap] = *(const float4*)&w_lds[i*144 + tap*16 + og*4];
                #pragma unroll
                for (int u = 0; u < 2; ++u)
                    #pragma unroll
                    for (int dy = 0; dy < 3; ++dy)
                        #pragma unroll
                        for (int dx = 0; dx < 3; ++dx) {
                            const float4 ww = w4[dy*3 + dx];
                            #pragma unroll
                            for (int v = 0; v < 4; ++v) {
                                const float xv = xr[u + dy][v + dx];
                                acc[og*4 + 0][u][v] += xv * ww.x;
                                acc[og*4 + 1][u][v] += xv * ww.y;
                                acc[og*4 + 2][u][v] += xv * ww.z;
                                acc[og*4 + 3][u][v] += xv * ww.w;
                            }
                        }
            }
        }
    }

    // epilogue: add modulated bias, coalesced float4 stores
    #pragma unroll
    for (int ol = 0; ol < 16; ++ol) {
        const int o = oh*16 + ol;
        const float bm = biasmod[o];
        #pragma unroll
        for (int u = 0; u < 2; ++u) {
            const int y  = y0 + 2*ty + u;
            const int xx = x0 + tx4*4;
            float4 r;
            r.x = acc[ol][u][0] + bm;
            r.y = acc[ol][u][1] + bm;
            r.z = acc[ol][u][2] + bm;
            r.w = acc[ol][u][3] + bm;
            *(float4*)&out[((size_t)(b*COUT + o)*H_ + y)*W_ + xx] = r;
        }
    }
}

extern "C" void kernel_launch(void* const* d_in, const int* in_sizes, int n_in,
                              void* d_out, int out_size, void* d_ws, size_t ws_size,
                              hipStream_t stream) {
    const float* x       = (const float*)d_in[0];
    const float* cond    = (const float*)d_in[1];
    const float* lpe     = (const float*)d_in[2];
    const float* weights = (const float*)d_in[3];
    const float* bias    = (const float*)d_in[4];
    const float* wa_w    = (const float*)d_in[5];
    const float* wa_b    = (const float*)d_in[6];
    const float* ba_w    = (const float*)d_in[7];
    const float* ba_b    = (const float*)d_in[8];
    float* out = (float*)d_out;
    float* ws  = (float*)d_ws;   // 1024 floats: wadapt[16][32] | biasmod[16][32]

    adapt_kernel<<<dim3(B_), dim3(256), 0, stream>>>(
        cond, lpe, wa_w, wa_b, ba_w, ba_b, bias, ws);

    conv_kernel<<<dim3(W_/TILE_W, H_/TILE_H, B_*2), dim3(256), 0, stream>>>(
        x, weights, ws, out);
}

// Round 2
// 277.867 us; speedup vs baseline: 2.5124x; 2.5124x over previous
//
#include <hip/hip_runtime.h>

// BatchAdaptiveConv2d via implicit GEMM on bf16 MFMA.
// out[b,o,y,x] = sum_{i,dy,dx} x[b,i,y+dy-1,x+dx-1] * W[i,o,dy,dx]*wadapt[b,i]
//               + bias[o]*badapt[b,o]
// R2: 9 shifted K=32 GEMMs with mfma_f32_16x16x32_bf16.
//  A = scaled weights Bm[tap][o][i] (m=out), B = x tile (n=pixel), fp32 acc.
//  x staged in LDS as [pixel][channel] bf16, 64 B/pixel, 16B-chunk XOR swizzle
//  (kg ^ ((p>>1)&3)) -> staging writes AND fragment reads bank-uniform.
//  Rolling 8-row window over a 32-row x 64-col strip. HBM-bound target ~45us.

#define B_    16
#define CIN   32
#define COUT  32
#define H_    256
#define W_    256
#define EMB2  512

#define XPX       66            // 64 + 2 halo pixels per LDS row
#define PXS       32            // ushorts per pixel (32 ch * bf16)
#define ROWS_     (XPX*PXS)     // 2112 ushorts per LDS row
#define NSLOT     8

using short8  = __attribute__((ext_vector_type(8))) short;
using float4v = __attribute__((ext_vector_type(4))) float;

__device__ __forceinline__ unsigned short f2bf(float f) {
    unsigned u = __builtin_bit_cast(unsigned, f);
    u += 0x7FFFu + ((u >> 16) & 1u);      // RNE
    return (unsigned short)(u >> 16);
}
__device__ __forceinline__ unsigned pk2(float a, float b) {
    return (unsigned)f2bf(a) | ((unsigned)f2bf(b) << 16);
}

// ---------------- kernel 1: adapt coefficients ----------------
// ws[0..511] = wadapt[b][i]; ws[512..1023] = bias[o]*badapt[b][o]
__global__ __launch_bounds__(256) void adapt_kernel(
    const float* __restrict__ cond, const float* __restrict__ lpe,
    const float* __restrict__ wa_w, const float* __restrict__ wa_b,
    const float* __restrict__ ba_w, const float* __restrict__ ba_b,
    const float* __restrict__ bias, float* __restrict__ ws)
{
    __shared__ float iv[EMB2];
    __shared__ float partial[64][4];
    const int b = blockIdx.x;
    const int t = threadIdx.x;

    iv[t]       = cond[b*256 + t];
    iv[t + 256] = lpe[b*256 + t];
    __syncthreads();

    const int out  = t & 63;
    const int part = t >> 6;
    const float* row = (out < 32) ? (wa_w + out*EMB2) : (ba_w + (out-32)*EMB2);
    float s = 0.f;
    #pragma unroll 8
    for (int j = part*128; j < part*128 + 128; ++j) s += iv[j] * row[j];
    partial[out][part] = s;
    __syncthreads();

    if (t < 64) {
        float v = partial[t][0] + partial[t][1] + partial[t][2] + partial[t][3];
        if (t < 32) ws[b*32 + t] = v + wa_b[t];
        else {
            int o = t - 32;
            ws[512 + b*32 + o] = bias[o] * (v + ba_b[o]);
        }
    }
}

// ---------------- kernel 2: MFMA conv ----------------
// grid (W/64, H/32, B); block 256 = 4 waves. Wave w handles output row 4t+w.
__global__ __launch_bounds__(256, 2) void conv_kernel(
    const float* __restrict__ x, const float* __restrict__ weights,
    const float* __restrict__ ws, float* __restrict__ out)
{
    __shared__ unsigned short xbuf[NSLOT * ROWS_];   // 33792 B
    __shared__ unsigned short wbuf[9 * COUT * PXS];  // 18432 B

    const int tid    = threadIdx.x;
    const int lane   = tid & 63;
    const int w      = tid >> 6;
    const int ln15   = lane & 15;
    const int kg     = lane >> 4;        // k-group 0..3
    const int xstrip = blockIdx.x * 64;
    const int ystrip = blockIdx.y * 32;
    const int b      = blockIdx.z;

    // ---- build scaled-weight LDS: wbuf[tap*1024 + o*32 + i] ----
    for (int idx = tid; idx < CIN*COUT*9; idx += 256) {
        int i   = idx / 288;
        int rem = idx - i*288;
        int o   = rem / 9;
        int tap = rem - o*9;
        float v = weights[idx] * ws[b*32 + i];
        wbuf[tap*1024 + o*32 + i] = f2bf(v);
    }

    // ---- staging helper: rows r0..r0+nrows-1 (relative), with halo+zeros ----
    auto stage = [&](int r0, int nrows) {
        const int total = nrows * XPX * 4;
        for (int idx = tid; idx < total; idx += 256) {
            int p  = idx % XPX;
            int t2 = idx / XPX;
            int g  = t2 & 3;              // channel group
            int rr = t2 >> 2;
            int r  = r0 + rr;
            int gy = ystrip + r;
            int gx = xstrip + p - 1;
            int slot = (r + 1) & 7;
            unsigned dst = slot*ROWS_ + p*PXS + ((g ^ ((p >> 1) & 3)) * 8);
            uint4 pk;
            if (((unsigned)gy < 256u) & ((unsigned)gx < 256u)) {
                const float* src = x + (((size_t)(b*CIN + g*8) << 16) + (gy << 8) + gx);
                float f0 = src[0*65536], f1 = src[1*65536];
                float f2 = src[2*65536], f3 = src[3*65536];
                float f4 = src[4*65536], f5 = src[5*65536];
                float f6 = src[6*65536], f7 = src[7*65536];
                pk.x = pk2(f0, f1); pk.y = pk2(f2, f3);
                pk.z = pk2(f4, f5); pk.w = pk2(f6, f7);
            } else {
                pk = uint4{0u, 0u, 0u, 0u};
            }
            *(uint4*)&xbuf[dst] = pk;
        }
    };

    stage(-1, 6);                 // rows -1..4 for iteration 0
    __syncthreads();

    // ---- hoist weight A-fragments (lane: m=out=ln15, k=kg*8+j) ----
    short8 wA[9][2];
    #pragma unroll
    for (int tap = 0; tap < 9; ++tap)
        #pragma unroll
        for (int ot = 0; ot < 2; ++ot) {
            int o = ot*16 + ln15;
            wA[tap][ot] = *(const short8*)&wbuf[tap*1024 + o*32 + kg*8];
        }

    // ---- per-lane modulated bias (out = ot*16 + (lane>>4)*4 + r) ----
    float bm[2][4];
    #pragma unroll
    for (int ot = 0; ot < 2; ++ot)
        #pragma unroll
        for (int r = 0; r < 4; ++r)
            bm[ot][r] = ws[512 + b*32 + ot*16 + kg*4 + r];

    for (int t = 0; t < 8; ++t) {
        if (t > 0) {
            stage(4*t + 1, 4);
            __syncthreads();
        }

        const int orow = 4*t + w;             // this wave's output row
        const int gy   = ystrip + orow;

        float4v acc[4][2];
        #pragma unroll
        for (int c = 0; c < 4; ++c) {
            acc[c][0] = float4v{0.f, 0.f, 0.f, 0.f};
            acc[c][1] = float4v{0.f, 0.f, 0.f, 0.f};
        }

        #pragma unroll
        for (int dy = 0; dy < 3; ++dy) {
            const int rowbase = ((orow + dy) & 7) * ROWS_;
            #pragma unroll
            for (int dx = 0; dx < 3; ++dx) {
                const int tap = dy*3 + dx;
                #pragma unroll
                for (int c = 0; c < 4; ++c) {
                    int p = c*16 + dx + ln15;            // LDS pixel index
                    int a = rowbase + p*PXS + ((kg ^ ((p >> 1) & 3)) * 8);
                    short8 xf = *(const short8*)&xbuf[a];
                    acc[c][0] = __builtin_amdgcn_mfma_f32_16x16x32_bf16(
                                    wA[tap][0], xf, acc[c][0], 0, 0, 0);
                    acc[c][1] = __builtin_amdgcn_mfma_f32_16x16x32_bf16(
                                    wA[tap][1], xf, acc[c][1], 0, 0, 0);
                }
            }
        }
        __syncthreads();   // all LDS reads done; next iter may restage

        // D: row(out) = kg*4 + r, col(pixel) = ln15
        #pragma unroll
        for (int c = 0; c < 4; ++c) {
            const int xcol = xstrip + c*16 + ln15;
            #pragma unroll
            for (int ot = 0; ot < 2; ++ot) {
                const int obase = ot*16 + kg*4;
                #pragma unroll
                for (int r = 0; r < 4; ++r) {
                    out[(((size_t)(b*COUT + obase + r) << 8) + gy << 8) + xcol] =
                        acc[c][ot][r] + bm[ot][r];
                }
            }
        }
    }
}

extern "C" void kernel_launch(void* const* d_in, const int* in_sizes, int n_in,
                              void* d_out, int out_size, void* d_ws, size_t ws_size,
                              hipStream_t stream) {
    const float* x       = (const float*)d_in[0];
    const float* cond    = (const float*)d_in[1];
    const float* lpe     = (const float*)d_in[2];
    const float* weights = (const float*)d_in[3];
    const float* bias    = (const float*)d_in[4];
    const float* wa_w    = (const float*)d_in[5];
    const float* wa_b    = (const float*)d_in[6];
    const float* ba_w    = (const float*)d_in[7];
    const float* ba_b    = (const float*)d_in[8];
    float* outp = (float*)d_out;
    float* ws   = (float*)d_ws;    // 1024 floats: wadapt | bias*badapt

    adapt_kernel<<<dim3(B_), dim3(256), 0, stream>>>(
        cond, lpe, wa_w, wa_b, ba_w, ba_b, bias, ws);

    conv_kernel<<<dim3(W_/64, H_/32, B_), dim3(256), 0, stream>>>(
        x, weights, ws, outp);
}